// Round 1
// baseline (520.724 us; speedup 1.0000x reference)
//
#include <hip/hip_runtime.h>

#define BB 16
#define NT 2048
#define NC 2048
#define DIM 256
#define INDIM 128

typedef unsigned short u16;
typedef __bf16 bfx8 __attribute__((ext_vector_type(8)));
typedef float f32x4 __attribute__((ext_vector_type(4)));

__device__ __forceinline__ u16 f2bf(float f) {
    union { float f; unsigned u; } v; v.f = f;
    return (u16)((v.u + 0x7FFFu + ((v.u >> 16) & 1u)) >> 16);
}

#define MFMA16(a, b, c) __builtin_amdgcn_mfma_f32_16x16x32_bf16((a), (b), (c), 0, 0, 0)

// ---------------- converts ----------------

__global__ void cvt_bf16_kernel(const float* __restrict__ in, u16* __restrict__ out, int n4) {
    int i = blockIdx.x * blockDim.x + threadIdx.x;
    if (i >= n4) return;
    float4 v = reinterpret_cast<const float4*>(in)[i];
    ushort4 o;
    o.x = f2bf(v.x); o.y = f2bf(v.y); o.z = f2bf(v.z); o.w = f2bf(v.w);
    reinterpret_cast<ushort4*>(out)[i] = o;
}

// w [K][256] fp32 -> wt [256][K] bf16
__global__ void cvt_w_kernel(const float* __restrict__ w, u16* __restrict__ wt, int K) {
    int idx = blockIdx.x * 256 + threadIdx.x;
    if (idx >= K * 256) return;
    int n = idx / K, k = idx - n * K;
    wt[idx] = f2bf(w[k * 256 + n]);
}

// r [B][NC][DIM] fp32 -> rt [B][DIM][NC] bf16
__global__ void cvt_rt_kernel(const float* __restrict__ r, u16* __restrict__ rt) {
    __shared__ u16 tile[32][33];
    int b = blockIdx.z;
    int c0 = blockIdx.x * 32, d0 = blockIdx.y * 32;
    int tx = threadIdx.x, ty = threadIdx.y; // (32, 8)
    const float* rb = r + (size_t)b * NC * DIM;
#pragma unroll
    for (int i = 0; i < 4; i++) {
        int c = c0 + ty + i * 8;
        tile[ty + i * 8][tx] = f2bf(rb[(size_t)c * DIM + d0 + tx]);
    }
    __syncthreads();
    u16* rtb = rt + (size_t)b * DIM * NC;
#pragma unroll
    for (int i = 0; i < 4; i++) {
        int d = d0 + ty + i * 8;
        rtb[(size_t)d * NC + c0 + tx] = tile[tx][ty + i * 8];
    }
}

// ---------------- MLP GEMM: C[M,256] = act(A[M,K] @ Wt[256,K]^T + bias) ----------------

template <int K, bool RELU>
__global__ __launch_bounds__(256) void gemm_mlp(const u16* __restrict__ A,
                                                const u16* __restrict__ Wt,
                                                const float* __restrict__ bias,
                                                u16* __restrict__ C) {
    int tid = threadIdx.x;
    int lane = tid & 63, wid = tid >> 6;
    int wr = wid >> 1, wc = wid & 1;
    int m0 = blockIdx.x * 128 + wr * 64;
    int n0 = blockIdx.y * 128 + wc * 64;
    int lr = lane & 15, lg = lane >> 4;

    f32x4 acc[4][4] = {};
#pragma unroll
    for (int ks = 0; ks < K / 32; ks++) {
        bfx8 a[4], b[4];
#pragma unroll
        for (int mt = 0; mt < 4; mt++)
            a[mt] = *reinterpret_cast<const bfx8*>(A + (size_t)(m0 + mt * 16 + lr) * K + ks * 32 + lg * 8);
#pragma unroll
        for (int nt = 0; nt < 4; nt++)
            b[nt] = *reinterpret_cast<const bfx8*>(Wt + (size_t)(n0 + nt * 16 + lr) * K + ks * 32 + lg * 8);
#pragma unroll
        for (int mt = 0; mt < 4; mt++)
#pragma unroll
            for (int nt = 0; nt < 4; nt++)
                acc[mt][nt] = MFMA16(a[mt], b[nt], acc[mt][nt]);
    }
#pragma unroll
    for (int nt = 0; nt < 4; nt++) {
        int col = n0 + nt * 16 + lr;
        float bv = bias[col];
#pragma unroll
        for (int mt = 0; mt < 4; mt++) {
            int rowb = m0 + mt * 16 + lg * 4;
#pragma unroll
            for (int r = 0; r < 4; r++) {
                float v = acc[mt][nt][r] + bv;
                if (RELU) v = fmaxf(v, 0.0f);
                C[(size_t)(rowb + r) * 256 + col] = f2bf(v);
            }
        }
    }
}

// ---------------- pass 1: column stats m_c, 1/l_c ----------------
// grid (NC/64, B), 256 threads. Block owns 64 columns; k-tile held in registers; q streamed.

__global__ __launch_bounds__(256) void stats_kernel(const u16* __restrict__ q,
                                                    const u16* __restrict__ k,
                                                    float* __restrict__ gm,
                                                    float* __restrict__ gl) {
    int b = blockIdx.y;
    int c0 = blockIdx.x * 64;
    int tid = threadIdx.x, lane = tid & 63, w = tid >> 6;
    int lr = lane & 15, lg = lane >> 4;
    const u16* qb = q + (size_t)b * NT * DIM;
    const u16* kb = k + (size_t)b * NC * DIM;
    const float scale = 1.0f / 16.0f;

    bfx8 kf[4][8];
#pragma unroll
    for (int j = 0; j < 4; j++)
#pragma unroll
        for (int ks = 0; ks < 8; ks++)
            kf[j][ks] = *reinterpret_cast<const bfx8*>(kb + (size_t)(c0 + j * 16 + lr) * DIM + ks * 32 + lg * 8);

    float m_run[4], l_run[4];
#pragma unroll
    for (int j = 0; j < 4; j++) { m_run[j] = -1e30f; l_run[j] = 0.0f; }

    for (int ts = 0; ts < NT / 64; ts++) {
        int t0 = ts * 64 + w * 16;
        f32x4 acc[4] = {};
#pragma unroll
        for (int ks = 0; ks < 8; ks++) {
            bfx8 a = *reinterpret_cast<const bfx8*>(qb + (size_t)(t0 + lr) * DIM + ks * 32 + lg * 8);
#pragma unroll
            for (int j = 0; j < 4; j++)
                acc[j] = MFMA16(a, kf[j][ks], acc[j]);
        }
#pragma unroll
        for (int j = 0; j < 4; j++) {
            float s0 = acc[j][0] * scale, s1 = acc[j][1] * scale;
            float s2 = acc[j][2] * scale, s3 = acc[j][3] * scale;
            float mx = fmaxf(fmaxf(s0, s1), fmaxf(s2, s3));
            mx = fmaxf(mx, __shfl_xor(mx, 16));
            mx = fmaxf(mx, __shfl_xor(mx, 32));
            float m_new = fmaxf(m_run[j], mx);
            float p = __expf(s0 - m_new) + __expf(s1 - m_new) + __expf(s2 - m_new) + __expf(s3 - m_new);
            p += __shfl_xor(p, 16);
            p += __shfl_xor(p, 32);
            l_run[j] = l_run[j] * __expf(m_run[j] - m_new) + p;
            m_run[j] = m_new;
        }
    }

    __shared__ float sm[4][64], sl[4][64];
    if (lg == 0) {
#pragma unroll
        for (int j = 0; j < 4; j++) {
            sm[w][j * 16 + lr] = m_run[j];
            sl[w][j * 16 + lr] = l_run[j];
        }
    }
    __syncthreads();
    if (tid < 64) {
        float mf = sm[0][tid];
#pragma unroll
        for (int ww = 1; ww < 4; ww++) mf = fmaxf(mf, sm[ww][tid]);
        float lf = 0.0f;
#pragma unroll
        for (int ww = 0; ww < 4; ww++) lf += sl[ww][tid] * __expf(sm[ww][tid] - mf);
        gm[(size_t)b * NC + c0 + tid] = mf;
        gl[(size_t)b * NC + c0 + tid] = 1.0f / lf;
    }
}

// ---------------- pass 2: out[t,d] = sum_c exp(S-m_c)/l_c * r[c,d] ----------------
// grid (NT/64, B), 256 threads (4 waves). Wave w: S rows [16w,16w+16), out cols [64w,64w+64).

__global__ __launch_bounds__(256) void attn_kernel(const u16* __restrict__ q,
                                                   const u16* __restrict__ k,
                                                   const u16* __restrict__ rt,
                                                   const float* __restrict__ gm,
                                                   const float* __restrict__ gl,
                                                   float* __restrict__ out) {
    int b = blockIdx.y;
    int t0 = blockIdx.x * 64;
    int tid = threadIdx.x, lane = tid & 63, w = tid >> 6;
    int lr = lane & 15, lg = lane >> 4;
    const u16* qb = q + (size_t)b * NT * DIM;
    const u16* kb = k + (size_t)b * NC * DIM;
    const u16* rtb = rt + (size_t)b * DIM * NC;

    __shared__ float sm[NC], sl[NC];
    __shared__ u16 pl[64][32];
    {
        const float4* gmb = reinterpret_cast<const float4*>(gm + (size_t)b * NC);
        const float4* glb = reinterpret_cast<const float4*>(gl + (size_t)b * NC);
        for (int i = tid; i < NC / 4; i += 256) {
            reinterpret_cast<float4*>(sm)[i] = gmb[i];
            reinterpret_cast<float4*>(sl)[i] = glb[i];
        }
    }
    __syncthreads();

    // hoist q fragments (wave's 16 rows, full K=256)
    bfx8 aq[8];
#pragma unroll
    for (int ks = 0; ks < 8; ks++)
        aq[ks] = *reinterpret_cast<const bfx8*>(qb + (size_t)(t0 + w * 16 + lr) * DIM + ks * 32 + lg * 8);

    const float scale = 1.0f / 16.0f;
    f32x4 acc[4][4] = {};

    for (int c0 = 0; c0 < NC; c0 += 32) {
        // S phase
        f32x4 s[2] = {};
#pragma unroll
        for (int ks = 0; ks < 8; ks++) {
#pragma unroll
            for (int j = 0; j < 2; j++) {
                bfx8 bb = *reinterpret_cast<const bfx8*>(kb + (size_t)(c0 + j * 16 + lr) * DIM + ks * 32 + lg * 8);
                s[j] = MFMA16(aq[ks], bb, s[j]);
            }
        }
#pragma unroll
        for (int j = 0; j < 2; j++) {
            int c = c0 + j * 16 + lr;
            float mv = sm[c], lv = sl[c];
            int trow = w * 16 + lg * 4;
#pragma unroll
            for (int r = 0; r < 4; r++) {
                float p = __expf(s[j][r] * scale - mv) * lv;
                pl[trow + r][j * 16 + lr] = f2bf(p);
            }
        }
        __syncthreads();
        // PV phase
        bfx8 pa[4], rb[4];
#pragma unroll
        for (int mt = 0; mt < 4; mt++)
            pa[mt] = *reinterpret_cast<const bfx8*>(&pl[mt * 16 + lr][lg * 8]);
#pragma unroll
        for (int nt = 0; nt < 4; nt++)
            rb[nt] = *reinterpret_cast<const bfx8*>(rtb + (size_t)(w * 64 + nt * 16 + lr) * NC + c0 + lg * 8);
#pragma unroll
        for (int mt = 0; mt < 4; mt++)
#pragma unroll
            for (int nt = 0; nt < 4; nt++)
                acc[mt][nt] = MFMA16(pa[mt], rb[nt], acc[mt][nt]);
        __syncthreads();
    }

    float* ob = out + (size_t)b * NT * DIM;
#pragma unroll
    for (int nt = 0; nt < 4; nt++) {
        int col = w * 64 + nt * 16 + lr;
#pragma unroll
        for (int mt = 0; mt < 4; mt++) {
            int rowb = t0 + mt * 16 + lg * 4;
#pragma unroll
            for (int r = 0; r < 4; r++)
                ob[(size_t)(rowb + r) * DIM + col] = acc[mt][nt][r];
        }
    }
}

// ---------------- launch ----------------

extern "C" void kernel_launch(void* const* d_in, const int* in_sizes, int n_in,
                              void* d_out, int out_size, void* d_ws, size_t ws_size,
                              hipStream_t stream) {
    const float* xc  = (const float*)d_in[0];
    const float* xt  = (const float*)d_in[1];
    const float* ri  = (const float*)d_in[2];
    const float* qw1 = (const float*)d_in[3];  const float* qb1 = (const float*)d_in[4];
    const float* qw2 = (const float*)d_in[5];  const float* qb2 = (const float*)d_in[6];
    const float* qw3 = (const float*)d_in[7];  const float* qb3 = (const float*)d_in[8];
    const float* kw1 = (const float*)d_in[9];  const float* kb1 = (const float*)d_in[10];
    const float* kw2 = (const float*)d_in[11]; const float* kb2 = (const float*)d_in[12];
    const float* kw3 = (const float*)d_in[13]; const float* kb3 = (const float*)d_in[14];

    if (ws_size < ((size_t)67 << 20)) return;  // need ~65.3 MB

    char* ws = (char*)d_ws;
    u16* q    = (u16*)(ws);                         // 16 MB: q bf16 [B][NT][DIM]
    u16* kk   = (u16*)(ws + ((size_t)16 << 20));    // 16 MB: k bf16 [B][NC][DIM]
    u16* tmp1 = (u16*)(ws + ((size_t)32 << 20));    // 16 MB: x / h2 / rt
    u16* tmp2 = (u16*)(ws + ((size_t)48 << 20));    // 16 MB: h1
    u16* wbuf = (u16*)(ws + ((size_t)64 << 20));    // 640 KB weights
    u16* qw1t = wbuf;
    u16* qw2t = qw1t + 32768;
    u16* qw3t = qw2t + 65536;
    u16* kw1t = qw3t + 65536;
    u16* kw2t = kw1t + 32768;
    u16* kw3t = kw2t + 65536;
    float* gm = (float*)(ws + ((size_t)65 << 20));
    float* gl = gm + BB * NC;

    // weights -> transposed bf16
    cvt_w_kernel<<<dim3(128), 256, 0, stream>>>(qw1, qw1t, 128);
    cvt_w_kernel<<<dim3(256), 256, 0, stream>>>(qw2, qw2t, 256);
    cvt_w_kernel<<<dim3(256), 256, 0, stream>>>(qw3, qw3t, 256);
    cvt_w_kernel<<<dim3(128), 256, 0, stream>>>(kw1, kw1t, 128);
    cvt_w_kernel<<<dim3(256), 256, 0, stream>>>(kw2, kw2t, 256);
    cvt_w_kernel<<<dim3(256), 256, 0, stream>>>(kw3, kw3t, 256);

    // q-MLP
    cvt_bf16_kernel<<<4096, 256, 0, stream>>>(xt, tmp1, (BB * NT * INDIM) / 4);
    gemm_mlp<128, true ><<<dim3(256, 2), 256, 0, stream>>>(tmp1, qw1t, qb1, tmp2);
    gemm_mlp<256, true ><<<dim3(256, 2), 256, 0, stream>>>(tmp2, qw2t, qb2, tmp1);
    gemm_mlp<256, false><<<dim3(256, 2), 256, 0, stream>>>(tmp1, qw3t, qb3, q);

    // k-MLP
    cvt_bf16_kernel<<<4096, 256, 0, stream>>>(xc, tmp1, (BB * NC * INDIM) / 4);
    gemm_mlp<128, true ><<<dim3(256, 2), 256, 0, stream>>>(tmp1, kw1t, kb1, tmp2);
    gemm_mlp<256, true ><<<dim3(256, 2), 256, 0, stream>>>(tmp2, kw2t, kb2, tmp1);
    gemm_mlp<256, false><<<dim3(256, 2), 256, 0, stream>>>(tmp1, kw3t, kb3, kk);

    // r_i -> rt (transposed bf16)
    cvt_rt_kernel<<<dim3(64, 8, BB), dim3(32, 8), 0, stream>>>(ri, tmp1);

    // pass 1: column stats
    stats_kernel<<<dim3(NC / 64, BB), 256, 0, stream>>>(q, kk, gm, gl);

    // pass 2: attention output
    attn_kernel<<<dim3(NT / 64, BB), 256, 0, stream>>>(q, kk, tmp1, gm, gl, (float*)d_out);
}